// Round 2
// baseline (263.465 us; speedup 1.0000x reference)
//
#include <hip/hip_runtime.h>

#define EPS_BN 1e-5f

// Problem: B=64, N=1024, C=32, O=64, K=16. The kNN/top-k/gather in the
// reference is dead code (gather source is constant along the gathered axis
// -> neigh[b,n,k,:] == x[b,n,:] for all k), so the mean over k is identity.
// out[b,o,n] = gelu(bn3(W3 . gelu(bn2(W2 . gelu(bn1(W1 . x[b,n,:]))))))[o]
// All inputs/outputs are float32 (reference dtype; R1 NaN diagnosed f32-as-bf16
// misread: rsqrt of sign-garbled "variance").

__device__ __forceinline__ float gelu(float v) {
    return 0.5f * v * (1.0f + erff(v * 0.7071067811865476f));
}

// Fold BN (inference) into weights + bias, f32 in workspace:
//   ws[0:2048)      W1f[o][c] = W1[o][c] * s1[o]          (64x32)
//   ws[2048:6144)   W2f[o][c] = W2[o][c] * s2[o]          (64x64)
//   ws[6144:10240)  W3f[o][c] = W3[o][c] * s3[o]          (64x64)
//   ws[10240:10304) bias1[o] = b1[o] - m1[o]*s1[o]
//   ws[10304:10368) bias2
//   ws[10368:10432) bias3
__global__ __launch_bounds__(256)
void prep_kernel(const float* __restrict__ W1,
                 const float* __restrict__ g1, const float* __restrict__ bb1,
                 const float* __restrict__ m1, const float* __restrict__ v1,
                 const float* __restrict__ W2,
                 const float* __restrict__ g2, const float* __restrict__ bb2,
                 const float* __restrict__ m2, const float* __restrict__ v2,
                 const float* __restrict__ W3,
                 const float* __restrict__ g3, const float* __restrict__ bb3,
                 const float* __restrict__ m3, const float* __restrict__ v3,
                 float* __restrict__ ws)
{
    int gid = blockIdx.x * blockDim.x + threadIdx.x;
    if (gid < 2048) {
        int o = gid >> 5;
        float s = g1[o] * rsqrtf(v1[o] + EPS_BN);
        ws[gid] = W1[gid] * s;
    } else if (gid < 6144) {
        int i = gid - 2048; int o = i >> 6;
        float s = g2[o] * rsqrtf(v2[o] + EPS_BN);
        ws[gid] = W2[i] * s;
    } else if (gid < 10240) {
        int i = gid - 6144; int o = i >> 6;
        float s = g3[o] * rsqrtf(v3[o] + EPS_BN);
        ws[gid] = W3[i] * s;
    } else if (gid < 10304) {
        int o = gid - 10240;
        float s = g1[o] * rsqrtf(v1[o] + EPS_BN);
        ws[gid] = bb1[o] - m1[o] * s;
    } else if (gid < 10368) {
        int o = gid - 10304;
        float s = g2[o] * rsqrtf(v2[o] + EPS_BN);
        ws[gid] = bb2[o] - m2[o] * s;
    } else if (gid < 10432) {
        int o = gid - 10368;
        float s = g3[o] * rsqrtf(v3[o] + EPS_BN);
        ws[gid] = bb3[o] - m3[o] * s;
    }
}

// One thread per point; activations in registers; weights via wave-uniform
// f32 loads from the folded workspace (scalar-cache friendly).
__global__ __launch_bounds__(256)
void mlp_kernel(const float* __restrict__ x,
                const float* __restrict__ ws,
                float* __restrict__ out)
{
    const int p = blockIdx.x * 256 + threadIdx.x;   // 0..65535
    const int b = p >> 10;
    const int n = p & 1023;

    // ---- load x[p, 0:32] as 8x float4 (coalesced 16B/lane) ----
    float xr[32];
    const float4* xp = (const float4*)(x + (size_t)p * 32);
#pragma unroll
    for (int i = 0; i < 8; ++i) {
        float4 u = xp[i];
        xr[i*4+0] = u.x; xr[i*4+1] = u.y; xr[i*4+2] = u.z; xr[i*4+3] = u.w;
    }

    const float* __restrict__ W1f = ws;
    const float* __restrict__ W2f = ws + 2048;
    const float* __restrict__ W3f = ws + 6144;
    const float* __restrict__ bias1 = ws + 10240;
    const float* __restrict__ bias2 = ws + 10304;
    const float* __restrict__ bias3 = ws + 10368;

    // ---- stage 1: 32 -> 64 ----
    float y[64];
#pragma unroll 8
    for (int o = 0; o < 64; ++o) {
        const float* w = W1f + o * 32;
        float acc = bias1[o];
#pragma unroll
        for (int c = 0; c < 32; ++c) acc = fmaf(w[c], xr[c], acc);
        y[o] = gelu(acc);
    }

    // ---- stage 2: 64 -> 64 ----
    float z[64];
#pragma unroll 4
    for (int o = 0; o < 64; ++o) {
        const float* w = W2f + o * 64;
        float acc = bias2[o];
#pragma unroll
        for (int c = 0; c < 64; ++c) acc = fmaf(w[c], y[c], acc);
        z[o] = gelu(acc);
    }

    // ---- stage 3: 64 -> 64, store transposed out[b, o, n] (coalesced in n) ----
    float* op = out + (size_t)b * 64 * 1024 + n;
#pragma unroll 4
    for (int o = 0; o < 64; ++o) {
        const float* w = W3f + o * 64;
        float acc = bias3[o];
#pragma unroll
        for (int c = 0; c < 64; ++c) acc = fmaf(w[c], z[c], acc);
        op[(size_t)o * 1024] = gelu(acc);
    }
}

extern "C" void kernel_launch(void* const* d_in, const int* in_sizes, int n_in,
                              void* d_out, int out_size, void* d_ws, size_t ws_size,
                              hipStream_t stream) {
    const float* x  = (const float*)d_in[0];
    const float* W1 = (const float*)d_in[1];
    const float* g1 = (const float*)d_in[2];
    const float* b1 = (const float*)d_in[3];
    const float* m1 = (const float*)d_in[4];
    const float* v1 = (const float*)d_in[5];
    const float* W2 = (const float*)d_in[6];
    const float* g2 = (const float*)d_in[7];
    const float* b2 = (const float*)d_in[8];
    const float* m2 = (const float*)d_in[9];
    const float* v2 = (const float*)d_in[10];
    const float* W3 = (const float*)d_in[11];
    const float* g3 = (const float*)d_in[12];
    const float* b3 = (const float*)d_in[13];
    const float* m3 = (const float*)d_in[14];
    const float* v3 = (const float*)d_in[15];
    float* ws = (float*)d_ws;
    float* out = (float*)d_out;

    prep_kernel<<<41, 256, 0, stream>>>(W1, g1, b1, m1, v1,
                                        W2, g2, b2, m2, v2,
                                        W3, g3, b3, m3, v3, ws);
    mlp_kernel<<<256, 256, 0, stream>>>(x, ws, out);
}

// Round 3
// 114.739 us; speedup vs baseline: 2.2962x; 2.2962x over previous
//
#include <hip/hip_runtime.h>

#define EPS_BN 1e-5f

// B=64, N=1024, C=32, O=64, K=16. kNN/gather in the reference is dead code
// (neigh == x for all k) so mean over k is identity:
// out[b,o,n] = gelu(bn3(W3.gelu(bn2(W2.gelu(bn1(W1.x[b,n,:]))))))[o], all f32.
//
// R2 post-mortem: 1 thread/point -> 4 waves/CU (Occupancy 11%, VALUBusy 26%).
// R3: 4 threads/point (16 outputs each), activations via LDS ping-pong,
// wave-uniform weight slices via transposed weights + readfirstlane -> s_load.

__device__ __forceinline__ float gelu(float v) {
    return 0.5f * v * (1.0f + erff(v * 0.7071067811865476f));
}

// ws layout (floats), weights TRANSPOSED to [c][o] and BN-folded:
//   [0,2048)      W1t[c*64+o] = W1[o*32+c] * s1[o]   (32x64)
//   [2048,6144)   W2t[c*64+o] = W2[o*64+c] * s2[o]   (64x64)
//   [6144,10240)  W3t[c*64+o] = W3[o*64+c] * s3[o]   (64x64)
//   [10240,10304) bias1[o] = b1[o] - m1[o]*s1[o]
//   [10304,10368) bias2
//   [10368,10432) bias3
__global__ __launch_bounds__(256)
void prep_kernel(const float* __restrict__ W1,
                 const float* __restrict__ g1, const float* __restrict__ bb1,
                 const float* __restrict__ m1, const float* __restrict__ v1,
                 const float* __restrict__ W2,
                 const float* __restrict__ g2, const float* __restrict__ bb2,
                 const float* __restrict__ m2, const float* __restrict__ v2,
                 const float* __restrict__ W3,
                 const float* __restrict__ g3, const float* __restrict__ bb3,
                 const float* __restrict__ m3, const float* __restrict__ v3,
                 float* __restrict__ ws)
{
    int gid = blockIdx.x * blockDim.x + threadIdx.x;
    if (gid < 2048) {
        int c = gid >> 6, o = gid & 63;
        float s = g1[o] * rsqrtf(v1[o] + EPS_BN);
        ws[gid] = W1[o * 32 + c] * s;
    } else if (gid < 6144) {
        int i = gid - 2048; int c = i >> 6, o = i & 63;
        float s = g2[o] * rsqrtf(v2[o] + EPS_BN);
        ws[gid] = W2[o * 64 + c] * s;
    } else if (gid < 10240) {
        int i = gid - 6144; int c = i >> 6, o = i & 63;
        float s = g3[o] * rsqrtf(v3[o] + EPS_BN);
        ws[gid] = W3[o * 64 + c] * s;
    } else if (gid < 10304) {
        int o = gid - 10240;
        float s = g1[o] * rsqrtf(v1[o] + EPS_BN);
        ws[gid] = bb1[o] - m1[o] * s;
    } else if (gid < 10368) {
        int o = gid - 10304;
        float s = g2[o] * rsqrtf(v2[o] + EPS_BN);
        ws[gid] = bb2[o] - m2[o] * s;
    } else if (gid < 10432) {
        int o = gid - 10368;
        float s = g3[o] * rsqrtf(v3[o] + EPS_BN);
        ws[gid] = bb3[o] - m3[o] * s;
    }
}

// Block: 256 threads = 64 points x 4 output-slices of 16.
// lane p = tid&63 (point), wave w = tid>>6 owns outputs [16w, 16w+16).
// LDS: buf0 = x-tile (stride 33) then reused as z-tile (stride 65);
//      buf1 = y-tile (stride 65). All b32 access, 2-way bank = free.
__global__ __launch_bounds__(256, 4)
void mlp_kernel(const float* __restrict__ x,
                const float* __restrict__ ws,
                float* __restrict__ out)
{
    __shared__ float buf0[64 * 65];   // 16.25 KB (x-tile uses 64*33 of it)
    __shared__ float buf1[64 * 65];   // 16.25 KB

    const int tid = threadIdx.x;
    const int p = tid & 63;                               // point within tile
    const int o0 = __builtin_amdgcn_readfirstlane((tid >> 6) << 4);  // wave-uniform

    // ---- stage x-load: 64 points x 32 ch = 512 float4, 2 per thread ----
    const float4* xb = (const float4*)(x + (size_t)blockIdx.x * 64 * 32);
#pragma unroll
    for (int r = 0; r < 2; ++r) {
        int i4 = tid + r * 256;            // 0..511
        float4 v = xb[i4];
        int pp = i4 >> 3;                  // (i4*4)/32
        int cc = (i4 << 2) & 31;
        buf0[pp * 33 + cc + 0] = v.x;
        buf0[pp * 33 + cc + 1] = v.y;
        buf0[pp * 33 + cc + 2] = v.z;
        buf0[pp * 33 + cc + 3] = v.w;
    }
    __syncthreads();

    const float* __restrict__ W1t = ws;
    const float* __restrict__ W2t = ws + 2048;
    const float* __restrict__ W3t = ws + 6144;
    const float* __restrict__ bias1 = ws + 10240;
    const float* __restrict__ bias2 = ws + 10304;
    const float* __restrict__ bias3 = ws + 10368;

    float acc[16];

    // ---- stage 1: 32 -> 64 ----
#pragma unroll
    for (int j = 0; j < 16; ++j) acc[j] = bias1[o0 + j];
#pragma unroll 4
    for (int c = 0; c < 32; ++c) {
        float a = buf0[p * 33 + c];
        const float* w = W1t + c * 64 + o0;   // wave-uniform -> s_load_dwordx16
#pragma unroll
        for (int j = 0; j < 16; ++j) acc[j] = fmaf(w[j], a, acc[j]);
    }
    __syncthreads();   // buf1 free to write (it was never read, but keep order w/ buf0 reuse below)
#pragma unroll
    for (int j = 0; j < 16; ++j) buf1[p * 65 + o0 + j] = gelu(acc[j]);
    __syncthreads();

    // ---- stage 2: 64 -> 64 ----
#pragma unroll
    for (int j = 0; j < 16; ++j) acc[j] = bias2[o0 + j];
#pragma unroll 4
    for (int c = 0; c < 64; ++c) {
        float a = buf1[p * 65 + c];
        const float* w = W2t + c * 64 + o0;
#pragma unroll
        for (int j = 0; j < 16; ++j) acc[j] = fmaf(w[j], a, acc[j]);
    }
    __syncthreads();   // buf0 x-tile fully consumed; reuse as z-tile
#pragma unroll
    for (int j = 0; j < 16; ++j) buf0[p * 65 + o0 + j] = gelu(acc[j]);
    __syncthreads();

    // ---- stage 3: 64 -> 64, store out[b, o, n] ----
#pragma unroll
    for (int j = 0; j < 16; ++j) acc[j] = bias3[o0 + j];
#pragma unroll 4
    for (int c = 0; c < 64; ++c) {
        float a = buf0[p * 65 + c];
        const float* w = W3t + c * 64 + o0;
#pragma unroll
        for (int j = 0; j < 16; ++j) acc[j] = fmaf(w[j], a, acc[j]);
    }

    const int pg = blockIdx.x * 64 + p;       // global point id
    const int b = pg >> 10;
    const int n = pg & 1023;
    float* op = out + (size_t)b * 64 * 1024 + n;
#pragma unroll
    for (int j = 0; j < 16; ++j)
        op[(size_t)(o0 + j) * 1024] = gelu(acc[j]);
}

extern "C" void kernel_launch(void* const* d_in, const int* in_sizes, int n_in,
                              void* d_out, int out_size, void* d_ws, size_t ws_size,
                              hipStream_t stream) {
    const float* x  = (const float*)d_in[0];
    const float* W1 = (const float*)d_in[1];
    const float* g1 = (const float*)d_in[2];
    const float* b1 = (const float*)d_in[3];
    const float* m1 = (const float*)d_in[4];
    const float* v1 = (const float*)d_in[5];
    const float* W2 = (const float*)d_in[6];
    const float* g2 = (const float*)d_in[7];
    const float* b2 = (const float*)d_in[8];
    const float* m2 = (const float*)d_in[9];
    const float* v2 = (const float*)d_in[10];
    const float* W3 = (const float*)d_in[11];
    const float* g3 = (const float*)d_in[12];
    const float* b3 = (const float*)d_in[13];
    const float* m3 = (const float*)d_in[14];
    const float* v3 = (const float*)d_in[15];
    float* ws = (float*)d_ws;
    float* out = (float*)d_out;

    prep_kernel<<<41, 256, 0, stream>>>(W1, g1, b1, m1, v1,
                                        W2, g2, b2, m2, v2,
                                        W3, g3, b3, m3, v3, ws);
    mlp_kernel<<<1024, 256, 0, stream>>>(x, ws, out);
}

// Round 4
// 100.665 us; speedup vs baseline: 2.6172x; 1.1398x over previous
//
#include <hip/hip_runtime.h>

#define EPS_BN 1e-5f

// B=64, N=1024, C=32, O=64, K=16. kNN/gather in the reference is dead code
// (neigh == x for all k) so mean over k is identity:
// out[b,o,n] = gelu(bn3(W3.gelu(bn2(W2.gelu(bn1(W1.x[b,n,:]))))))[o], all f32 I/O.
//
// R3 post-mortem: f32 VALU path is floor-limited at ~8.5us (671M MACs / 157TF)
// and the s_load weight stream stalled it to ~100us. R4: bf16 MFMA 16x16x32.
// prep folds BN into weights and emits them in B-fragment lane order (bf16);
// mlp stages them to LDS once per block, each wave runs 16 points through all
// 3 stages with wave-private LDS act tiles for the C/D->A layout round-trip.

typedef __attribute__((ext_vector_type(8))) short short8;   // 8 bf16 = 4 VGPRs
typedef __attribute__((ext_vector_type(4))) float f32x4;

__device__ __forceinline__ unsigned short f2bf(float f) {   // RNE f32->bf16
    unsigned int u = __float_as_uint(f);
    u += 0x7fffu + ((u >> 16) & 1u);
    return (unsigned short)(u >> 16);
}

__device__ __forceinline__ float gelu(float v) {
    return 0.5f * v * (1.0f + erff(v * 0.7071067811865476f));
}

// ws layout (bytes):
//   [0, 20480)      10240 bf16 weights in B-fragment order:
//     stage1 @elem 0:    [t:4][kk:1][lane:64][j:8]  W1f[o=16t+(lane&15)][c=(lane>>4)*8+j]
//     stage2 @elem 2048: [t:4][kk:2][lane:64][j:8]  W2f[o][c=32kk+(lane>>4)*8+j]
//     stage3 @elem 6144: same shape as stage2
//   [20480, 21248)  192 f32 biases: bias[s][o] = b_s[o] - m_s[o]*scale_s[o]
__global__ __launch_bounds__(256)
void prep_kernel(const float* __restrict__ W1,
                 const float* __restrict__ g1, const float* __restrict__ bb1,
                 const float* __restrict__ m1, const float* __restrict__ v1,
                 const float* __restrict__ W2,
                 const float* __restrict__ g2, const float* __restrict__ bb2,
                 const float* __restrict__ m2, const float* __restrict__ v2,
                 const float* __restrict__ W3,
                 const float* __restrict__ g3, const float* __restrict__ bb3,
                 const float* __restrict__ m3, const float* __restrict__ v3,
                 void* __restrict__ wsv)
{
    unsigned short* wf = (unsigned short*)wsv;
    float* wb = (float*)((char*)wsv + 20480);
    int gid = blockIdx.x * blockDim.x + threadIdx.x;

    if (gid < 2048) {                       // stage 1: K=32
        int t = gid >> 9, r = gid & 511;
        int lane = r >> 3, j = r & 7;
        int o = t * 16 + (lane & 15);
        int c = (lane >> 4) * 8 + j;
        float s = g1[o] * rsqrtf(v1[o] + EPS_BN);
        wf[gid] = f2bf(W1[o * 32 + c] * s);
    } else if (gid < 6144) {                // stage 2: K=64
        int rel = gid - 2048;
        int t = rel >> 10, r2 = rel & 1023;
        int kk = r2 >> 9, r3 = r2 & 511;
        int lane = r3 >> 3, j = r3 & 7;
        int o = t * 16 + (lane & 15);
        int c = kk * 32 + (lane >> 4) * 8 + j;
        float s = g2[o] * rsqrtf(v2[o] + EPS_BN);
        wf[gid] = f2bf(W2[o * 64 + c] * s);
    } else if (gid < 10240) {               // stage 3: K=64
        int rel = gid - 6144;
        int t = rel >> 10, r2 = rel & 1023;
        int kk = r2 >> 9, r3 = r2 & 511;
        int lane = r3 >> 3, j = r3 & 7;
        int o = t * 16 + (lane & 15);
        int c = kk * 32 + (lane >> 4) * 8 + j;
        float s = g3[o] * rsqrtf(v3[o] + EPS_BN);
        wf[gid] = f2bf(W3[o * 64 + c] * s);
    } else if (gid < 10432) {               // biases
        int i = gid - 10240;
        int s = i >> 6, o = i & 63;
        const float* gg = (s == 0) ? g1 : (s == 1) ? g2 : g3;
        const float* vv = (s == 0) ? v1 : (s == 1) ? v2 : v3;
        const float* bbp = (s == 0) ? bb1 : (s == 1) ? bb2 : bb3;
        const float* mm = (s == 0) ? m1 : (s == 1) ? m2 : m3;
        float sc = gg[o] * rsqrtf(vv[o] + EPS_BN);
        wb[i] = bbp[o] - mm[o] * sc;
    }
}

// Block = 256 threads = 4 waves; each wave owns one 16-point m-tile.
// Grid = 1024 blocks (4096 m-tiles). LDS: 20.5KB weights (block-shared) +
// per-wave act tile (16x72 bf16, [p][o]) + per-wave f32 transpose tile (16x20).
// MFMA layouts (measured, m89/m120): A[m=lane&15][k=(lane>>4)*8+j],
// B[k=(lane>>4)*8+j][n=lane&15], C/D: col(n)=lane&15, row(m)=(lane>>4)*4+reg.
__global__ __launch_bounds__(256, 4)
void mlp_mfma(const float* __restrict__ x,
              const void* __restrict__ wsv,
              float* __restrict__ out)
{
    const unsigned short* wfrag = (const unsigned short*)wsv;
    const float* wbias = (const float*)((const char*)wsv + 20480);

    __shared__ uint4 smem4[2176];                                   // 34816 B
    unsigned short* wlds = (unsigned short*)smem4;                  // 20480 B
    unsigned short* actsb = (unsigned short*)((char*)smem4 + 20480);// 4 * 16*72 bf16
    float* otb = (float*)((char*)smem4 + 29696);                    // 4 * 16*20 f32

    const int tid = threadIdx.x;
    const int wave = tid >> 6, lane = tid & 63;
    const int q = lane >> 4, l15 = lane & 15;

    // ---- stage-in weights: 20480 B = 1280 uint4, 5 per thread ----
    {
        const uint4* src = (const uint4*)wfrag;
#pragma unroll
        for (int i = 0; i < 5; ++i) smem4[tid + i * 256] = src[tid + i * 256];
    }

    // per-lane biases (n = lane&15 within each 16-wide tile)
    float bias_r[3][4];
#pragma unroll
    for (int s = 0; s < 3; ++s)
#pragma unroll
        for (int t = 0; t < 4; ++t)
            bias_r[s][t] = wbias[s * 64 + t * 16 + l15];

    const int mtile = blockIdx.x * 4 + wave;
    const int p0 = mtile * 16;

    // ---- stage-1 A-frag straight from x (rows are contiguous 32 floats) ----
    const float4* xp = (const float4*)(x + (size_t)(p0 + l15) * 32 + q * 8);
    float4 xa = xp[0], xb = xp[1];
    short8 a1;
    a1[0] = (short)f2bf(xa.x); a1[1] = (short)f2bf(xa.y);
    a1[2] = (short)f2bf(xa.z); a1[3] = (short)f2bf(xa.w);
    a1[4] = (short)f2bf(xb.x); a1[5] = (short)f2bf(xb.y);
    a1[6] = (short)f2bf(xb.z); a1[7] = (short)f2bf(xb.w);

    __syncthreads();   // weights staged

    unsigned short* aw = actsb + wave * (16 * 72);
    float* ow = otb + wave * (16 * 20);

    // ---- stage 1: 32 -> 64, one MFMA per n-tile ----
#pragma unroll
    for (int t = 0; t < 4; ++t) {
        f32x4 acc = { bias_r[0][t], bias_r[0][t], bias_r[0][t], bias_r[0][t] };
        short8 bf = *(const short8*)(wlds + ((t * 64 + lane) << 3));
        acc = __builtin_amdgcn_mfma_f32_16x16x32_bf16(a1, bf, acc, 0, 0, 0);
#pragma unroll
        for (int r = 0; r < 4; ++r)
            aw[(q * 4 + r) * 72 + t * 16 + l15] = f2bf(gelu(acc[r]));
    }
    __threadfence_block();   // acts visible to cross-lane A-frag reads

    // ---- stage 2: 64 -> 64 ----
    short8 a20 = *(const short8*)(aw + l15 * 72 + q * 8);
    short8 a21 = *(const short8*)(aw + l15 * 72 + 32 + q * 8);
#pragma unroll
    for (int t = 0; t < 4; ++t) {
        f32x4 acc = { bias_r[1][t], bias_r[1][t], bias_r[1][t], bias_r[1][t] };
        short8 b0 = *(const short8*)(wlds + 2048 + ((t * 2 + 0) * 64 + lane) * 8);
        short8 b1 = *(const short8*)(wlds + 2048 + ((t * 2 + 1) * 64 + lane) * 8);
        acc = __builtin_amdgcn_mfma_f32_16x16x32_bf16(a20, b0, acc, 0, 0, 0);
        acc = __builtin_amdgcn_mfma_f32_16x16x32_bf16(a21, b1, acc, 0, 0, 0);
#pragma unroll
        for (int r = 0; r < 4; ++r)
            aw[(q * 4 + r) * 72 + t * 16 + l15] = f2bf(gelu(acc[r]));
    }
    __threadfence_block();

    // ---- stage 3: 64 -> 64, coalesced f32 store via small LDS transpose ----
    short8 a30 = *(const short8*)(aw + l15 * 72 + q * 8);
    short8 a31 = *(const short8*)(aw + l15 * 72 + 32 + q * 8);
    const int bb = p0 >> 10;
    const int n0 = p0 & 1023;
    float* outb = out + (size_t)bb * 65536 + n0;
#pragma unroll
    for (int t = 0; t < 4; ++t) {
        f32x4 acc = { bias_r[2][t], bias_r[2][t], bias_r[2][t], bias_r[2][t] };
        short8 b0 = *(const short8*)(wlds + 6144 + ((t * 2 + 0) * 64 + lane) * 8);
        short8 b1 = *(const short8*)(wlds + 6144 + ((t * 2 + 1) * 64 + lane) * 8);
        acc = __builtin_amdgcn_mfma_f32_16x16x32_bf16(a30, b0, acc, 0, 0, 0);
        acc = __builtin_amdgcn_mfma_f32_16x16x32_bf16(a31, b1, acc, 0, 0, 0);
        // write [o'][p] tile (o' = n within tile = l15, p = q*4+r)
#pragma unroll
        for (int r = 0; r < 4; ++r)
            ow[l15 * 20 + q * 4 + r] = gelu(acc[r]);
        __threadfence_block();
        // read back row-major: lane -> (o' = lane>>2, 4 cols at (lane&3)*4)
        float4 v = *(const float4*)(ow + (lane >> 2) * 20 + (lane & 3) * 4);
        *(float4*)(outb + (size_t)(t * 16 + (lane >> 2)) * 1024 + (lane & 3) * 4) = v;
        __threadfence_block();   // don't let next t's writes pass this read
    }
}

extern "C" void kernel_launch(void* const* d_in, const int* in_sizes, int n_in,
                              void* d_out, int out_size, void* d_ws, size_t ws_size,
                              hipStream_t stream) {
    const float* x  = (const float*)d_in[0];
    const float* W1 = (const float*)d_in[1];
    const float* g1 = (const float*)d_in[2];
    const float* b1 = (const float*)d_in[3];
    const float* m1 = (const float*)d_in[4];
    const float* v1 = (const float*)d_in[5];
    const float* W2 = (const float*)d_in[6];
    const float* g2 = (const float*)d_in[7];
    const float* b2 = (const float*)d_in[8];
    const float* m2 = (const float*)d_in[9];
    const float* v2 = (const float*)d_in[10];
    const float* W3 = (const float*)d_in[11];
    const float* g3 = (const float*)d_in[12];
    const float* b3 = (const float*)d_in[13];
    const float* m3 = (const float*)d_in[14];
    const float* v3 = (const float*)d_in[15];
    float* out = (float*)d_out;

    prep_kernel<<<41, 256, 0, stream>>>(W1, g1, b1, m1, v1,
                                        W2, g2, b2, m2, v2,
                                        W3, g3, b3, m3, v3, d_ws);
    mlp_mfma<<<1024, 256, 0, stream>>>(x, d_ws, out);
}

// Round 5
// 99.252 us; speedup vs baseline: 2.6545x; 1.0142x over previous
//
#include <hip/hip_runtime.h>

#define EPS_BN 1e-5f

// B=64, N=1024, C=32, O=64, K=16. kNN/gather in the reference is dead code
// (neigh == x for all k) so mean over k is identity:
// out[b,o,n] = gelu(bn3(W3.gelu(bn2(W2.gelu(bn1(W1.x[b,n,:]))))))[o], all f32 I/O.
//
// R4 post-mortem: mlp_mfma ~10us (inferred; harness fills dominate dur_us).
// GELU via exact erff was ~4us of VALU (48 evals/lane x ~30 ops). R5: tanh-form
// GELU on HW exp2/rcp (~10 ops, branchless, saturation-safe) — rest unchanged.

typedef __attribute__((ext_vector_type(8))) short short8;   // 8 bf16 = 4 VGPRs
typedef __attribute__((ext_vector_type(4))) float f32x4;

__device__ __forceinline__ unsigned short f2bf(float f) {   // RNE f32->bf16
    unsigned int u = __float_as_uint(f);
    u += 0x7fffu + ((u >> 16) & 1u);
    return (unsigned short)(u >> 16);
}

// exact gelu for reference/prep-free paths (unused in hot loop now)
__device__ __forceinline__ float gelu_exact(float v) {
    return 0.5f * v * (1.0f + erff(v * 0.7071067811865476f));
}

// tanh-approx gelu, branchless, HW exp2 + rcp.
// t = tanh(u) = 1 - 2/(exp2(u*2*log2e)+1); u = 0.7978845608*(v+0.044715 v^3)
// k1 = 0.7978845608 * 2 * 1.4426950409 = 2.3022082
// inf-safe: exp2->inf => rcp(inf)=0 => t=1;  exp2->0 => t=-1.
__device__ __forceinline__ float gelu(float v) {
    float v2 = v * v;
    float inner = fmaf(0.044715f, v2, 1.0f);
    float m = (v * 2.3022082f) * inner;
    float z = __builtin_amdgcn_exp2f(m);
    float r = __builtin_amdgcn_rcpf(z + 1.0f);
    float t = fmaf(-2.0f, r, 1.0f);
    float h = 0.5f * v;
    return fmaf(h, t, h);
}

// ws layout (bytes):
//   [0, 20480)      10240 bf16 weights in B-fragment order:
//     stage1 @elem 0:    [t:4][kk:1][lane:64][j:8]  W1f[o=16t+(lane&15)][c=(lane>>4)*8+j]
//     stage2 @elem 2048: [t:4][kk:2][lane:64][j:8]  W2f[o][c=32kk+(lane>>4)*8+j]
//     stage3 @elem 6144: same shape as stage2
//   [20480, 21248)  192 f32 biases: bias[s][o] = b_s[o] - m_s[o]*scale_s[o]
__global__ __launch_bounds__(256)
void prep_kernel(const float* __restrict__ W1,
                 const float* __restrict__ g1, const float* __restrict__ bb1,
                 const float* __restrict__ m1, const float* __restrict__ v1,
                 const float* __restrict__ W2,
                 const float* __restrict__ g2, const float* __restrict__ bb2,
                 const float* __restrict__ m2, const float* __restrict__ v2,
                 const float* __restrict__ W3,
                 const float* __restrict__ g3, const float* __restrict__ bb3,
                 const float* __restrict__ m3, const float* __restrict__ v3,
                 void* __restrict__ wsv)
{
    unsigned short* wf = (unsigned short*)wsv;
    float* wb = (float*)((char*)wsv + 20480);
    int gid = blockIdx.x * blockDim.x + threadIdx.x;

    if (gid < 2048) {                       // stage 1: K=32
        int t = gid >> 9, r = gid & 511;
        int lane = r >> 3, j = r & 7;
        int o = t * 16 + (lane & 15);
        int c = (lane >> 4) * 8 + j;
        float s = g1[o] * rsqrtf(v1[o] + EPS_BN);
        wf[gid] = f2bf(W1[o * 32 + c] * s);
    } else if (gid < 6144) {                // stage 2: K=64
        int rel = gid - 2048;
        int t = rel >> 10, r2 = rel & 1023;
        int kk = r2 >> 9, r3 = r2 & 511;
        int lane = r3 >> 3, j = r3 & 7;
        int o = t * 16 + (lane & 15);
        int c = kk * 32 + (lane >> 4) * 8 + j;
        float s = g2[o] * rsqrtf(v2[o] + EPS_BN);
        wf[gid] = f2bf(W2[o * 64 + c] * s);
    } else if (gid < 10240) {               // stage 3: K=64
        int rel = gid - 6144;
        int t = rel >> 10, r2 = rel & 1023;
        int kk = r2 >> 9, r3 = r2 & 511;
        int lane = r3 >> 3, j = r3 & 7;
        int o = t * 16 + (lane & 15);
        int c = kk * 32 + (lane >> 4) * 8 + j;
        float s = g3[o] * rsqrtf(v3[o] + EPS_BN);
        wf[gid] = f2bf(W3[o * 64 + c] * s);
    } else if (gid < 10432) {               // biases
        int i = gid - 10240;
        int s = i >> 6, o = i & 63;
        const float* gg = (s == 0) ? g1 : (s == 1) ? g2 : g3;
        const float* vv = (s == 0) ? v1 : (s == 1) ? v2 : v3;
        const float* bbp = (s == 0) ? bb1 : (s == 1) ? bb2 : bb3;
        const float* mm = (s == 0) ? m1 : (s == 1) ? m2 : m3;
        float sc = gg[o] * rsqrtf(vv[o] + EPS_BN);
        wb[i] = bbp[o] - mm[o] * sc;
    }
}

// Block = 256 threads = 4 waves; each wave owns one 16-point m-tile.
// Grid = 1024 blocks (4096 m-tiles). LDS: 20.5KB weights (block-shared) +
// per-wave act tile (16x72 bf16, [p][o]) + per-wave f32 transpose tile (16x20).
// MFMA layouts (measured, m89/m120): A[m=lane&15][k=(lane>>4)*8+j],
// B[k=(lane>>4)*8+j][n=lane&15], C/D: col(n)=lane&15, row(m)=(lane>>4)*4+reg.
__global__ __launch_bounds__(256, 4)
void mlp_mfma(const float* __restrict__ x,
              const void* __restrict__ wsv,
              float* __restrict__ out)
{
    const unsigned short* wfrag = (const unsigned short*)wsv;
    const float* wbias = (const float*)((const char*)wsv + 20480);

    __shared__ uint4 smem4[2176];                                   // 34816 B
    unsigned short* wlds = (unsigned short*)smem4;                  // 20480 B
    unsigned short* actsb = (unsigned short*)((char*)smem4 + 20480);// 4 * 16*72 bf16
    float* otb = (float*)((char*)smem4 + 29696);                    // 4 * 16*20 f32

    const int tid = threadIdx.x;
    const int wave = tid >> 6, lane = tid & 63;
    const int q = lane >> 4, l15 = lane & 15;

    // ---- stage-in weights: 20480 B = 1280 uint4, 5 per thread ----
    {
        const uint4* src = (const uint4*)wfrag;
#pragma unroll
        for (int i = 0; i < 5; ++i) smem4[tid + i * 256] = src[tid + i * 256];
    }

    // per-lane biases (n = lane&15 within each 16-wide tile)
    float bias_r[3][4];
#pragma unroll
    for (int s = 0; s < 3; ++s)
#pragma unroll
        for (int t = 0; t < 4; ++t)
            bias_r[s][t] = wbias[s * 64 + t * 16 + l15];

    const int mtile = blockIdx.x * 4 + wave;
    const int p0 = mtile * 16;

    // ---- stage-1 A-frag straight from x (rows are contiguous 32 floats) ----
    const float4* xp = (const float4*)(x + (size_t)(p0 + l15) * 32 + q * 8);
    float4 xa = xp[0], xb = xp[1];
    short8 a1;
    a1[0] = (short)f2bf(xa.x); a1[1] = (short)f2bf(xa.y);
    a1[2] = (short)f2bf(xa.z); a1[3] = (short)f2bf(xa.w);
    a1[4] = (short)f2bf(xb.x); a1[5] = (short)f2bf(xb.y);
    a1[6] = (short)f2bf(xb.z); a1[7] = (short)f2bf(xb.w);

    __syncthreads();   // weights staged

    unsigned short* aw = actsb + wave * (16 * 72);
    float* ow = otb + wave * (16 * 20);

    // ---- stage 1: 32 -> 64, one MFMA per n-tile ----
#pragma unroll
    for (int t = 0; t < 4; ++t) {
        f32x4 acc = { bias_r[0][t], bias_r[0][t], bias_r[0][t], bias_r[0][t] };
        short8 bf = *(const short8*)(wlds + ((t * 64 + lane) << 3));
        acc = __builtin_amdgcn_mfma_f32_16x16x32_bf16(a1, bf, acc, 0, 0, 0);
#pragma unroll
        for (int r = 0; r < 4; ++r)
            aw[(q * 4 + r) * 72 + t * 16 + l15] = f2bf(gelu(acc[r]));
    }
    __threadfence_block();   // acts visible to cross-lane A-frag reads

    // ---- stage 2: 64 -> 64 ----
    short8 a20 = *(const short8*)(aw + l15 * 72 + q * 8);
    short8 a21 = *(const short8*)(aw + l15 * 72 + 32 + q * 8);
#pragma unroll
    for (int t = 0; t < 4; ++t) {
        f32x4 acc = { bias_r[1][t], bias_r[1][t], bias_r[1][t], bias_r[1][t] };
        short8 b0 = *(const short8*)(wlds + 2048 + ((t * 2 + 0) * 64 + lane) * 8);
        short8 b1 = *(const short8*)(wlds + 2048 + ((t * 2 + 1) * 64 + lane) * 8);
        acc = __builtin_amdgcn_mfma_f32_16x16x32_bf16(a20, b0, acc, 0, 0, 0);
        acc = __builtin_amdgcn_mfma_f32_16x16x32_bf16(a21, b1, acc, 0, 0, 0);
#pragma unroll
        for (int r = 0; r < 4; ++r)
            aw[(q * 4 + r) * 72 + t * 16 + l15] = f2bf(gelu(acc[r]));
    }
    __threadfence_block();

    // ---- stage 3: 64 -> 64, coalesced f32 store via small LDS transpose ----
    short8 a30 = *(const short8*)(aw + l15 * 72 + q * 8);
    short8 a31 = *(const short8*)(aw + l15 * 72 + 32 + q * 8);
    const int bb = p0 >> 10;
    const int n0 = p0 & 1023;
    float* outb = out + (size_t)bb * 65536 + n0;
#pragma unroll
    for (int t = 0; t < 4; ++t) {
        f32x4 acc = { bias_r[2][t], bias_r[2][t], bias_r[2][t], bias_r[2][t] };
        short8 b0 = *(const short8*)(wlds + 6144 + ((t * 2 + 0) * 64 + lane) * 8);
        short8 b1 = *(const short8*)(wlds + 6144 + ((t * 2 + 1) * 64 + lane) * 8);
        acc = __builtin_amdgcn_mfma_f32_16x16x32_bf16(a30, b0, acc, 0, 0, 0);
        acc = __builtin_amdgcn_mfma_f32_16x16x32_bf16(a31, b1, acc, 0, 0, 0);
        // write [o'][p] tile (o' = n within tile = l15, p = q*4+r)
#pragma unroll
        for (int r = 0; r < 4; ++r)
            ow[l15 * 20 + q * 4 + r] = gelu(acc[r]);
        __threadfence_block();
        // read back row-major: lane -> (o' = lane>>2, 4 cols at (lane&3)*4)
        float4 v = *(const float4*)(ow + (lane >> 2) * 20 + (lane & 3) * 4);
        *(float4*)(outb + (size_t)(t * 16 + (lane >> 2)) * 1024 + (lane & 3) * 4) = v;
        __threadfence_block();   // don't let next t's writes pass this read
    }
}

extern "C" void kernel_launch(void* const* d_in, const int* in_sizes, int n_in,
                              void* d_out, int out_size, void* d_ws, size_t ws_size,
                              hipStream_t stream) {
    const float* x  = (const float*)d_in[0];
    const float* W1 = (const float*)d_in[1];
    const float* g1 = (const float*)d_in[2];
    const float* b1 = (const float*)d_in[3];
    const float* m1 = (const float*)d_in[4];
    const float* v1 = (const float*)d_in[5];
    const float* W2 = (const float*)d_in[6];
    const float* g2 = (const float*)d_in[7];
    const float* b2 = (const float*)d_in[8];
    const float* m2 = (const float*)d_in[9];
    const float* v2 = (const float*)d_in[10];
    const float* W3 = (const float*)d_in[11];
    const float* g3 = (const float*)d_in[12];
    const float* b3 = (const float*)d_in[13];
    const float* m3 = (const float*)d_in[14];
    const float* v3 = (const float*)d_in[15];
    float* out = (float*)d_out;

    prep_kernel<<<41, 256, 0, stream>>>(W1, g1, b1, m1, v1,
                                        W2, g2, b2, m2, v2,
                                        W3, g3, b3, m3, v3, d_ws);
    mlp_mfma<<<1024, 256, 0, stream>>>(x, d_ws, out);
}

// Round 6
// 97.513 us; speedup vs baseline: 2.7018x; 1.0178x over previous
//
#include <hip/hip_runtime.h>

#define EPS_BN 1e-5f

// B=64, N=1024, C=32, O=64, K=16. kNN/gather in the reference is dead code
// (neigh == x for all k) so mean over k is identity:
// out[b,o,n] = gelu(bn3(W3.gelu(bn2(W2.gelu(bn1(W1.x[b,n,:]))))))[o], all f32 I/O.
//
// R5 post-mortem: dur is ~85us harness poison fills + ~14us ours (prep ~4 + mlp ~10).
// R6: fuse prep into mlp — each block folds BN into weights and swizzles into
// LDS B-fragment layout itself (40KB L2-resident raw weights, one ds_write_b64
// per source float4). Kills the prep dispatch. MFMA structure unchanged from R5.

typedef __attribute__((ext_vector_type(8))) short short8;   // 8 bf16 = 4 VGPRs
typedef __attribute__((ext_vector_type(4))) float f32x4;

__device__ __forceinline__ unsigned short f2bf(float f) {   // RNE f32->bf16
    unsigned int u = __float_as_uint(f);
    u += 0x7fffu + ((u >> 16) & 1u);
    return (unsigned short)(u >> 16);
}

// tanh-approx gelu, branchless, HW exp2 + rcp (R5-validated, absmax 7.8e-3).
__device__ __forceinline__ float gelu(float v) {
    float v2 = v * v;
    float inner = fmaf(0.044715f, v2, 1.0f);
    float m = (v * 2.3022082f) * inner;
    float z = __builtin_amdgcn_exp2f(m);
    float r = __builtin_amdgcn_rcpf(z + 1.0f);
    float t = fmaf(-2.0f, r, 1.0f);
    float h = 0.5f * v;
    return fmaf(h, t, h);
}

// Block = 256 threads = 4 waves; each wave owns one 16-point m-tile.
// Grid = 1024 blocks. LDS map (34816 B):
//   [0,20480)      wlds: bf16 weights in B-fragment order
//     stage1 @0:    [t:4][lane:64][j:8]        W1f[o=16t+(lane&15)][c=(lane>>4)*8+j]
//     stage2 @2048: [t:4][kk:2][lane:64][j:8]  W2f[o][c=32kk+(lane>>4)*8+j]
//     stage3 @6144: same shape as stage2
//   [20480,29696)  actsb: 4 waves x 16x72 bf16 act tiles ([p][o], pad 8)
//   [29696,34816)  otb:   4 waves x 16x20 f32 transpose tiles
//                  (aliased during fold phase as scb: 192 scales + 192 biases)
// MFMA layouts (measured, m89/m120): A[m=lane&15][k=(lane>>4)*8+j],
// B[k=(lane>>4)*8+j][n=lane&15], C/D: col(n)=lane&15, row(m)=(lane>>4)*4+reg.
__global__ __launch_bounds__(256, 4)
void mlp_fused(const float* __restrict__ x,
               const float* __restrict__ W1,
               const float* __restrict__ g1, const float* __restrict__ bb1,
               const float* __restrict__ m1, const float* __restrict__ v1,
               const float* __restrict__ W2,
               const float* __restrict__ g2, const float* __restrict__ bb2,
               const float* __restrict__ m2, const float* __restrict__ v2,
               const float* __restrict__ W3,
               const float* __restrict__ g3, const float* __restrict__ bb3,
               const float* __restrict__ m3, const float* __restrict__ v3,
               float* __restrict__ out)
{
    __shared__ uint4 smem4[2176];                                   // 34816 B
    unsigned short* wlds = (unsigned short*)smem4;                  // 20480 B
    unsigned short* actsb = (unsigned short*)((char*)smem4 + 20480);
    float* otb = (float*)((char*)smem4 + 29696);
    float* scb = otb;   // fold-phase alias: scb[0:192)=scales, scb[192:384)=biases

    const int tid = threadIdx.x;
    const int wave = tid >> 6, lane = tid & 63;
    const int q = lane >> 4, l15 = lane & 15;

    const int mtile = blockIdx.x * 4 + wave;
    const int p0 = mtile * 16;

    // ---- x prefetch (issue early; consumed after the fold barrier) ----
    const float4* xp = (const float4*)(x + (size_t)(p0 + l15) * 32 + q * 8);
    float4 xa = xp[0], xb = xp[1];

    // ---- fold phase A: 192 BN scale/bias terms ----
    if (tid < 192) {
        int s = tid >> 6, o = tid & 63;
        const float* gg  = (s == 0) ? g1  : (s == 1) ? g2  : g3;
        const float* vv  = (s == 0) ? v1  : (s == 1) ? v2  : v3;
        const float* bbp = (s == 0) ? bb1 : (s == 1) ? bb2 : bb3;
        const float* mm  = (s == 0) ? m1  : (s == 1) ? m2  : m3;
        float sc = gg[o] * rsqrtf(vv[o] + EPS_BN);
        scb[tid] = sc;
        scb[192 + tid] = bbp[o] - mm[o] * sc;
    }
    __syncthreads();

    // ---- fold phase B: coalesced raw-weight load -> swizzled bf16 LDS ----
    // Within each source float4 the 4 fragment-order dests are consecutive
    // and 8B-aligned -> one ds_write_b64 (as ushort[4] aliased uint2).
    // stage 1: 512 float4, 2/thread. s = o*32+c.
    {
        const float4* wv = (const float4*)W1;
#pragma unroll
        for (int r = 0; r < 2; ++r) {
            int e4 = tid + r * 256;
            float4 w = wv[e4];
            int s0 = e4 << 2;
            int o = s0 >> 5, c0 = s0 & 31;
            float sc = scb[o];
            int dst = ((o >> 4) << 9) + (((((c0 >> 3) << 4) | (o & 15))) << 3) + (c0 & 7);
            unsigned short pk[4] = { f2bf(w.x * sc), f2bf(w.y * sc),
                                     f2bf(w.z * sc), f2bf(w.w * sc) };
            *(uint2*)(wlds + dst) = *(const uint2*)pk;
        }
    }
    // stage 2: 1024 float4, 4/thread. s = o*64+c.
    {
        const float4* wv = (const float4*)W2;
#pragma unroll
        for (int r = 0; r < 4; ++r) {
            int e4 = tid + r * 256;
            float4 w = wv[e4];
            int s0 = e4 << 2;
            int o = s0 >> 6, c0 = s0 & 63;
            float sc = scb[64 + o];
            int dst = 2048 + ((o >> 4) << 10) + ((c0 >> 5) << 9)
                    + ((((((c0 >> 3) & 3) << 4) | (o & 15))) << 3) + (c0 & 7);
            unsigned short pk[4] = { f2bf(w.x * sc), f2bf(w.y * sc),
                                     f2bf(w.z * sc), f2bf(w.w * sc) };
            *(uint2*)(wlds + dst) = *(const uint2*)pk;
        }
    }
    // stage 3: 1024 float4, 4/thread.
    {
        const float4* wv = (const float4*)W3;
#pragma unroll
        for (int r = 0; r < 4; ++r) {
            int e4 = tid + r * 256;
            float4 w = wv[e4];
            int s0 = e4 << 2;
            int o = s0 >> 6, c0 = s0 & 63;
            float sc = scb[128 + o];
            int dst = 6144 + ((o >> 4) << 10) + ((c0 >> 5) << 9)
                    + ((((((c0 >> 3) & 3) << 4) | (o & 15))) << 3) + (c0 & 7);
            unsigned short pk[4] = { f2bf(w.x * sc), f2bf(w.y * sc),
                                     f2bf(w.z * sc), f2bf(w.w * sc) };
            *(uint2*)(wlds + dst) = *(const uint2*)pk;
        }
    }
    __syncthreads();   // weights folded+staged; scb still intact (otb unused yet)

    // per-lane biases (read BEFORE stage-3 overwrites the otb alias)
    float bias_r[3][4];
#pragma unroll
    for (int s = 0; s < 3; ++s)
#pragma unroll
        for (int t = 0; t < 4; ++t)
            bias_r[s][t] = scb[192 + s * 64 + t * 16 + l15];

    // ---- stage-1 A-frag from prefetched x ----
    short8 a1;
    a1[0] = (short)f2bf(xa.x); a1[1] = (short)f2bf(xa.y);
    a1[2] = (short)f2bf(xa.z); a1[3] = (short)f2bf(xa.w);
    a1[4] = (short)f2bf(xb.x); a1[5] = (short)f2bf(xb.y);
    a1[6] = (short)f2bf(xb.z); a1[7] = (short)f2bf(xb.w);

    unsigned short* aw = actsb + wave * (16 * 72);
    float* ow = otb + wave * (16 * 20);

    // ---- stage 1: 32 -> 64, one MFMA per n-tile ----
#pragma unroll
    for (int t = 0; t < 4; ++t) {
        f32x4 acc = { bias_r[0][t], bias_r[0][t], bias_r[0][t], bias_r[0][t] };
        short8 bf = *(const short8*)(wlds + ((t * 64 + lane) << 3));
        acc = __builtin_amdgcn_mfma_f32_16x16x32_bf16(a1, bf, acc, 0, 0, 0);
#pragma unroll
        for (int r = 0; r < 4; ++r)
            aw[(q * 4 + r) * 72 + t * 16 + l15] = f2bf(gelu(acc[r]));
    }
    __threadfence_block();   // acts visible to cross-lane A-frag reads

    // ---- stage 2: 64 -> 64 ----
    short8 a20 = *(const short8*)(aw + l15 * 72 + q * 8);
    short8 a21 = *(const short8*)(aw + l15 * 72 + 32 + q * 8);
#pragma unroll
    for (int t = 0; t < 4; ++t) {
        f32x4 acc = { bias_r[1][t], bias_r[1][t], bias_r[1][t], bias_r[1][t] };
        short8 b0 = *(const short8*)(wlds + 2048 + ((t * 2 + 0) * 64 + lane) * 8);
        short8 b1 = *(const short8*)(wlds + 2048 + ((t * 2 + 1) * 64 + lane) * 8);
        acc = __builtin_amdgcn_mfma_f32_16x16x32_bf16(a20, b0, acc, 0, 0, 0);
        acc = __builtin_amdgcn_mfma_f32_16x16x32_bf16(a21, b1, acc, 0, 0, 0);
#pragma unroll
        for (int r = 0; r < 4; ++r)
            aw[(q * 4 + r) * 72 + t * 16 + l15] = f2bf(gelu(acc[r]));
    }
    __threadfence_block();

    // ---- stage 3: 64 -> 64, coalesced f32 store via small LDS transpose ----
    short8 a30 = *(const short8*)(aw + l15 * 72 + q * 8);
    short8 a31 = *(const short8*)(aw + l15 * 72 + 32 + q * 8);
    const int bb = p0 >> 10;
    const int n0 = p0 & 1023;
    float* outb = out + (size_t)bb * 65536 + n0;
#pragma unroll
    for (int t = 0; t < 4; ++t) {
        f32x4 acc = { bias_r[2][t], bias_r[2][t], bias_r[2][t], bias_r[2][t] };
        short8 b0 = *(const short8*)(wlds + 6144 + ((t * 2 + 0) * 64 + lane) * 8);
        short8 b1 = *(const short8*)(wlds + 6144 + ((t * 2 + 1) * 64 + lane) * 8);
        acc = __builtin_amdgcn_mfma_f32_16x16x32_bf16(a30, b0, acc, 0, 0, 0);
        acc = __builtin_amdgcn_mfma_f32_16x16x32_bf16(a31, b1, acc, 0, 0, 0);
        // write [o'][p] tile (o' = n within tile = l15, p = q*4+r)
#pragma unroll
        for (int r = 0; r < 4; ++r)
            ow[l15 * 20 + q * 4 + r] = gelu(acc[r]);
        __threadfence_block();
        // read back row-major: lane -> (o' = lane>>2, 4 cols at (lane&3)*4)
        float4 v = *(const float4*)(ow + (lane >> 2) * 20 + (lane & 3) * 4);
        *(float4*)(outb + (size_t)(t * 16 + (lane >> 2)) * 1024 + (lane & 3) * 4) = v;
        __threadfence_block();   // don't let next t's writes pass this read
    }
}

extern "C" void kernel_launch(void* const* d_in, const int* in_sizes, int n_in,
                              void* d_out, int out_size, void* d_ws, size_t ws_size,
                              hipStream_t stream) {
    const float* x  = (const float*)d_in[0];
    const float* W1 = (const float*)d_in[1];
    const float* g1 = (const float*)d_in[2];
    const float* b1 = (const float*)d_in[3];
    const float* m1 = (const float*)d_in[4];
    const float* v1 = (const float*)d_in[5];
    const float* W2 = (const float*)d_in[6];
    const float* g2 = (const float*)d_in[7];
    const float* b2 = (const float*)d_in[8];
    const float* m2 = (const float*)d_in[9];
    const float* v2 = (const float*)d_in[10];
    const float* W3 = (const float*)d_in[11];
    const float* g3 = (const float*)d_in[12];
    const float* b3 = (const float*)d_in[13];
    const float* m3 = (const float*)d_in[14];
    const float* v3 = (const float*)d_in[15];
    float* out = (float*)d_out;

    mlp_fused<<<1024, 256, 0, stream>>>(x, W1, g1, b1, m1, v1,
                                        W2, g2, b2, m2, v2,
                                        W3, g3, b3, m3, v3, out);
}